// Round 7
// baseline (980.819 us; speedup 1.0000x reference)
//
#include <hip/hip_runtime.h>
#include <math.h>

#define BB 4
#define NN 4096
#define DEGQ 16
#define DDIM 128
#define EDIM 256
#define EE (NN*DEGQ)   // 65536
#define STR 68         // LDS row stride in floats (16B-aligned, padded)
#define STR4 17        // STR/4

// ws layout (in floats)
#define WS_XN     0
#define WS_UVPQ   (WS_XN + BB*NN*DDIM)            // per-node u,v,p,q: [B*N][768]
#define WS_SCORES (WS_UVPQ + (size_t)BB*NN*768)
#define WS_THR    (WS_SCORES + (size_t)BB*EE)     // 8 floats
#define WS_SELP   (WS_THR + 8)                    // 4 u32
#define WS_SELR   (WS_SELP + 4)                   // 4 i32
#define WS_GHIST  (WS_SELR + 4)                   // 1024 u32
#define WS_BN     (WS_GHIST + 1024)               // 768 floats
#define WS_WT     (WS_BN + 768)                   // k-packed weights: 81920 floats

// ---------------- normalize: one wave per node row ----------------
__global__ void k_norm(const float* __restrict__ nf, float* __restrict__ xn) {
    int wave = (blockIdx.x * blockDim.x + threadIdx.x) >> 6;
    int lane = threadIdx.x & 63;
    if (wave >= BB * NN) return;
    const float* row = nf + (size_t)wave * DDIM;
    float2 v = *(const float2*)(row + 2 * lane);
    float ss = v.x * v.x + v.y * v.y;
#pragma unroll
    for (int d = 32; d; d >>= 1) ss += __shfl_xor(ss, d, 64);
    float n = fmaxf(sqrtf(ss), 1e-12f);
    float inv = 1.0f / n;
    float2 o; o.x = v.x * inv; o.y = v.y * inv;
    *(float2*)(xn + (size_t)wave * DDIM + 2 * lane) = o;
}

// ---------------- BN constants + select-state init ----------------
__global__ void k_prep(const float* g1, const float* be1, const float* m1, const float* v1,
                       const float* g2, const float* be2, const float* m2, const float* v2,
                       float* bn, unsigned* ghist, unsigned* selp, int* selr) {
    int c = threadIdx.x;
    ghist[c] = 0u; ghist[256 + c] = 0u; ghist[512 + c] = 0u; ghist[768 + c] = 0u;
    if (c < 4) { selp[c] = 0u; selr[c] = EE / 2 - 1; }
    if (c < 256) {
        float s = g1[c] / sqrtf(v1[c] + 1e-5f);
        bn[c] = s; bn[256 + c] = be1[c] - m1[c] * s;
    }
    if (c < 128) {
        float s = g2[c] / sqrtf(v2[c] + 1e-5f);
        bn[512 + c] = s; bn[640 + c] = be2[c] - m2[c] * s;
    }
}

// ---------------- k-packed weight repack: wt[k4][c][kk] = W[k4*4+kk][c] ----------------
// seg A: Wa2 (128x128)   -> wt[0..16384)
// seg B: W1c (128x256)   -> wt[16384..49152)
// seg C: W2  (256x128)   -> wt[49152..81920)
__global__ void k_wt(const float* __restrict__ Wa2, const float* __restrict__ W1,
                     const float* __restrict__ W2, float* __restrict__ wt) {
    int i = blockIdx.x * 256 + threadIdx.x;
    if (i < 16384) {
        int k4 = i >> 9, r = i & 511, c = r >> 2, kk = r & 3;
        wt[i] = Wa2[(k4 * 4 + kk) * 128 + c];
    } else if (i < 49152) {
        int j = i - 16384;
        int k4 = j >> 10, r = j & 1023, c = r >> 2, kk = r & 3;
        wt[i] = W1[256 * 256 + (k4 * 4 + kk) * 256 + c];
    } else if (i < 81920) {
        int j = i - 49152;
        int k4 = j >> 9, r = j & 511, c = r >> 2, kk = r & 3;
        wt[i] = W2[(k4 * 4 + kk) * 128 + c];
    }
}

// ---------------- per-node u,v,p,q = xn @ {Wa1_top, Wa1_bot, W1a, W1b} ----------------
__global__ void k_uvpq(const float* __restrict__ xn, const float* __restrict__ Wa1,
                       const float* __restrict__ W1, float* __restrict__ uvpq) {
    int chunk = blockIdx.y;
    const float* wbase; int wstride; int ocol;
    switch (chunk) {
        case 0: wbase = Wa1;                 wstride = 128; ocol = 0;   break;
        case 1: wbase = Wa1 + 128 * 128;     wstride = 128; ocol = 128; break;
        case 2: wbase = W1;                  wstride = 256; ocol = 256; break;
        case 3: wbase = W1 + 128;            wstride = 256; ocol = 384; break;
        case 4: wbase = W1 + 128 * 256;      wstride = 256; ocol = 512; break;
        default: wbase = W1 + 128 * 256 + 128; wstride = 256; ocol = 640; break;
    }
    int wv = threadIdx.x >> 6, lane = threadIdx.x & 63;
    int nodebase = blockIdx.x * 32 + wv * 8;
    const float* xrow[8];
#pragma unroll
    for (int j = 0; j < 8; ++j) xrow[j] = xn + (size_t)(nodebase + j) * DDIM;
    float acc0[8] = {}, acc1[8] = {};
#pragma unroll 4
    for (int k = 0; k < 128; ++k) {
        float w0 = wbase[k * wstride + lane];
        float w1 = wbase[k * wstride + 64 + lane];
#pragma unroll
        for (int j = 0; j < 8; ++j) {
            float a = xrow[j][k];
            acc0[j] = fmaf(a, w0, acc0[j]);
            acc1[j] = fmaf(a, w1, acc1[j]);
        }
    }
#pragma unroll
    for (int j = 0; j < 8; ++j) {
        float* orow = uvpq + (size_t)(nodebase + j) * 768 + ocol;
        orow[lane] = acc0[j];
        orow[64 + lane] = acc1[j];
    }
}

// ---------------- fused edge pipeline: 64 edges/block, 8 waves (R2 structure) ----------
// LDS: h1T rows 0..127; gT rows 128..255; then h2T [256][STR] spans both.
// Weights from k-packed wt: one coalesced float4 per col per 4 k's.
__global__ __launch_bounds__(512) void
k_edge(const float* __restrict__ xn, const float* __restrict__ uvpq,
       const float* __restrict__ wt, const float* __restrict__ ba1,
       const float* __restrict__ ba2,
       const float* __restrict__ b1, const float* __restrict__ b2,
       const float* __restrict__ W3, const float* __restrict__ b3,
       const int* __restrict__ src, const int* __restrict__ tgt,
       const float* __restrict__ bn, float* __restrict__ scores) {
    __shared__ float smem[256 * STR];
    __shared__ int ssrc[64], stgt[64];
    int tid = threadIdx.x;
    int b = blockIdx.y;
    int T0 = blockIdx.x * 64;
    if (tid < 64) {
        ssrc[tid] = src[(size_t)b * EE + T0 + tid];
        stgt[tid] = tgt[(size_t)b * EE + T0 + tid];
    }
    __syncthreads();

    const float* uv = uvpq + (size_t)b * NN * 768;
    const float* xb = xn + (size_t)b * NN * DDIM;
    int wv = tid >> 6, lane = tid & 63;
    int ebase = 8 * wv;
    const float4* A4 = (const float4*)smem;
    const float4* waT = (const float4*)wt;              // [k4][128 cols]
    const float4* w1T = (const float4*)(wt + 16384);    // [k4][256 cols]
    const float4* w2T = (const float4*)(wt + 49152);    // [k4][128 cols]

    // phase h1: h1T[k][e] = relu(u_s[k] + v_t[k] + ba1[k]); wave w covers k in [16w,16w+16)
    {
        int k0 = 16 * wv;
        const float* urow = uv + (size_t)ssrc[lane] * 768 + k0;
        const float* vrow = uv + (size_t)stgt[lane] * 768 + 128 + k0;
#pragma unroll
        for (int it = 0; it < 16; ++it) {
            float h = urow[it] + vrow[it] + ba1[k0 + it];
            smem[(k0 + it) * STR + lane] = fmaxf(h, 0.0f);
        }
    }
    __syncthreads();

    // GEMV1: a = h1 @ Wa2 (+ba2), softmax over 128, gT[c][e] = |sf-tf|[c]*att[c]
    {
        float acc0[8] = {}, acc1[8] = {};
#pragma unroll 4
        for (int k4 = 0; k4 < 32; ++k4) {
            float4 w0v = waT[k4 * 128 + lane];
            float4 w1v = waT[k4 * 128 + 64 + lane];
            const float* w0p = (const float*)&w0v;
            const float* w1p = (const float*)&w1v;
#pragma unroll
            for (int kk = 0; kk < 4; ++kk) {
                int k = 4 * k4 + kk;
                float w0 = w0p[kk];
                float w1 = w1p[kk];
                float4 hA = A4[k * STR4 + 2 * wv];
                float4 hB = A4[k * STR4 + 2 * wv + 1];
                acc0[0] = fmaf(hA.x, w0, acc0[0]); acc1[0] = fmaf(hA.x, w1, acc1[0]);
                acc0[1] = fmaf(hA.y, w0, acc0[1]); acc1[1] = fmaf(hA.y, w1, acc1[1]);
                acc0[2] = fmaf(hA.z, w0, acc0[2]); acc1[2] = fmaf(hA.z, w1, acc1[2]);
                acc0[3] = fmaf(hA.w, w0, acc0[3]); acc1[3] = fmaf(hA.w, w1, acc1[3]);
                acc0[4] = fmaf(hB.x, w0, acc0[4]); acc1[4] = fmaf(hB.x, w1, acc1[4]);
                acc0[5] = fmaf(hB.y, w0, acc0[5]); acc1[5] = fmaf(hB.y, w1, acc1[5]);
                acc0[6] = fmaf(hB.z, w0, acc0[6]); acc1[6] = fmaf(hB.z, w1, acc1[6]);
                acc0[7] = fmaf(hB.w, w0, acc0[7]); acc1[7] = fmaf(hB.w, w1, acc1[7]);
            }
        }
        float bb0 = ba2[lane], bb1 = ba2[64 + lane];
#pragma unroll
        for (int j = 0; j < 8; ++j) {
            float a0 = acc0[j] + bb0, a1 = acc1[j] + bb1;
            float m = fmaxf(a0, a1);
#pragma unroll
            for (int d = 32; d; d >>= 1) m = fmaxf(m, __shfl_xor(m, d, 64));
            float p0 = expf(a0 - m), p1 = expf(a1 - m);
            float s = p0 + p1;
#pragma unroll
            for (int d = 32; d; d >>= 1) s += __shfl_xor(s, d, 64);
            float inv = 1.0f / s;
            int e = ebase + j;
            const float* xs = xb + (size_t)ssrc[e] * DDIM;
            const float* xt = xb + (size_t)stgt[e] * DDIM;
            float d0 = fabsf(xs[lane] - xt[lane]);
            float d1 = fabsf(xs[64 + lane] - xt[64 + lane]);
            smem[128 * STR + lane * STR + e] = d0 * p0 * inv;
            smem[128 * STR + (64 + lane) * STR + e] = d1 * p1 * inv;
        }
    }
    __syncthreads();

    // GEMV2: c = g @ W1c ; y = c + p_s + q_t + b1 ; h2 = relu(BN1)
    float acc2[8][4] = {};
    {
#pragma unroll 2
        for (int k4 = 0; k4 < 32; ++k4) {
            float4 wv0 = w1T[k4 * 256 + lane];
            float4 wv1 = w1T[k4 * 256 + 64 + lane];
            float4 wv2 = w1T[k4 * 256 + 128 + lane];
            float4 wv3 = w1T[k4 * 256 + 192 + lane];
            const float* p0 = (const float*)&wv0;
            const float* p1 = (const float*)&wv1;
            const float* p2 = (const float*)&wv2;
            const float* p3 = (const float*)&wv3;
#pragma unroll
            for (int kk = 0; kk < 4; ++kk) {
                int k = 4 * k4 + kk;
                float w0 = p0[kk], w1 = p1[kk], w2 = p2[kk], w3 = p3[kk];
                float4 gA = A4[128 * STR4 + k * STR4 + 2 * wv];
                float4 gB = A4[128 * STR4 + k * STR4 + 2 * wv + 1];
                acc2[0][0] = fmaf(gA.x, w0, acc2[0][0]); acc2[0][1] = fmaf(gA.x, w1, acc2[0][1]);
                acc2[0][2] = fmaf(gA.x, w2, acc2[0][2]); acc2[0][3] = fmaf(gA.x, w3, acc2[0][3]);
                acc2[1][0] = fmaf(gA.y, w0, acc2[1][0]); acc2[1][1] = fmaf(gA.y, w1, acc2[1][1]);
                acc2[1][2] = fmaf(gA.y, w2, acc2[1][2]); acc2[1][3] = fmaf(gA.y, w3, acc2[1][3]);
                acc2[2][0] = fmaf(gA.z, w0, acc2[2][0]); acc2[2][1] = fmaf(gA.z, w1, acc2[2][1]);
                acc2[2][2] = fmaf(gA.z, w2, acc2[2][2]); acc2[2][3] = fmaf(gA.z, w3, acc2[2][3]);
                acc2[3][0] = fmaf(gA.w, w0, acc2[3][0]); acc2[3][1] = fmaf(gA.w, w1, acc2[3][1]);
                acc2[3][2] = fmaf(gA.w, w2, acc2[3][2]); acc2[3][3] = fmaf(gA.w, w3, acc2[3][3]);
                acc2[4][0] = fmaf(gB.x, w0, acc2[4][0]); acc2[4][1] = fmaf(gB.x, w1, acc2[4][1]);
                acc2[4][2] = fmaf(gB.x, w2, acc2[4][2]); acc2[4][3] = fmaf(gB.x, w3, acc2[4][3]);
                acc2[5][0] = fmaf(gB.y, w0, acc2[5][0]); acc2[5][1] = fmaf(gB.y, w1, acc2[5][1]);
                acc2[5][2] = fmaf(gB.y, w2, acc2[5][2]); acc2[5][3] = fmaf(gB.y, w3, acc2[5][3]);
                acc2[6][0] = fmaf(gB.z, w0, acc2[6][0]); acc2[6][1] = fmaf(gB.z, w1, acc2[6][1]);
                acc2[6][2] = fmaf(gB.z, w2, acc2[6][2]); acc2[6][3] = fmaf(gB.z, w3, acc2[6][3]);
                acc2[7][0] = fmaf(gB.w, w0, acc2[7][0]); acc2[7][1] = fmaf(gB.w, w1, acc2[7][1]);
                acc2[7][2] = fmaf(gB.w, w2, acc2[7][2]); acc2[7][3] = fmaf(gB.w, w3, acc2[7][3]);
            }
        }
    }
    float s1v[4], t1v[4], b1v[4];
#pragma unroll
    for (int i = 0; i < 4; ++i) {
        int c = lane + 64 * i;
        s1v[i] = bn[c]; t1v[i] = bn[256 + c]; b1v[i] = b1[c];
    }
    __syncthreads();   // all gT reads done; smem reused as h2T [256][STR]
#pragma unroll
    for (int j = 0; j < 8; ++j) {
        int e = ebase + j;
        const float* pr = uv + (size_t)ssrc[e] * 768 + 256;
        const float* qr = uv + (size_t)stgt[e] * 768 + 512;
#pragma unroll
        for (int i = 0; i < 4; ++i) {
            int c = lane + 64 * i;
            float y = acc2[j][i] + pr[c] + qr[c] + b1v[i];
            smem[c * STR + e] = fmaxf(fmaf(y, s1v[i], t1v[i]), 0.0f);
        }
    }
    __syncthreads();

    // GEMV3: h3 = relu(BN2(h2 @ W2 + b2)); logit = h3 @ W3 + b3; score = sigmoid
    {
        float acc30[8] = {}, acc31[8] = {};
#pragma unroll 4
        for (int k4 = 0; k4 < 64; ++k4) {
            float4 w0v = w2T[k4 * 128 + lane];
            float4 w1v = w2T[k4 * 128 + 64 + lane];
            const float* w0p = (const float*)&w0v;
            const float* w1p = (const float*)&w1v;
#pragma unroll
            for (int kk = 0; kk < 4; ++kk) {
                int k = 4 * k4 + kk;
                float w0 = w0p[kk];
                float w1 = w1p[kk];
                float4 hA = A4[k * STR4 + 2 * wv];
                float4 hB = A4[k * STR4 + 2 * wv + 1];
                acc30[0] = fmaf(hA.x, w0, acc30[0]); acc31[0] = fmaf(hA.x, w1, acc31[0]);
                acc30[1] = fmaf(hA.y, w0, acc30[1]); acc31[1] = fmaf(hA.y, w1, acc31[1]);
                acc30[2] = fmaf(hA.z, w0, acc30[2]); acc31[2] = fmaf(hA.z, w1, acc31[2]);
                acc30[3] = fmaf(hA.w, w0, acc30[3]); acc31[3] = fmaf(hA.w, w1, acc31[3]);
                acc30[4] = fmaf(hB.x, w0, acc30[4]); acc31[4] = fmaf(hB.x, w1, acc31[4]);
                acc30[5] = fmaf(hB.y, w0, acc30[5]); acc31[5] = fmaf(hB.y, w1, acc31[5]);
                acc30[6] = fmaf(hB.z, w0, acc30[6]); acc31[6] = fmaf(hB.z, w1, acc31[6]);
                acc30[7] = fmaf(hB.w, w0, acc30[7]); acc31[7] = fmaf(hB.w, w1, acc31[7]);
            }
        }
        float s2a = bn[512 + lane], t2a = bn[640 + lane];
        float s2b = bn[512 + 64 + lane], t2b = bn[640 + 64 + lane];
        float b2a = b2[lane], b2b = b2[64 + lane];
        float w3a = W3[lane], w3b = W3[64 + lane];
        float b3v = b3[0];
#pragma unroll
        for (int j = 0; j < 8; ++j) {
            float h0 = fmaxf(fmaf(acc30[j] + b2a, s2a, t2a), 0.0f);
            float h1 = fmaxf(fmaf(acc31[j] + b2b, s2b, t2b), 0.0f);
            float lp = h0 * w3a + h1 * w3b;
#pragma unroll
            for (int d = 32; d; d >>= 1) lp += __shfl_xor(lp, d, 64);
            float sc = 1.0f / (1.0f + expf(-(lp + b3v)));
            if (lane == j) scores[(size_t)b * EE + T0 + ebase + j] = sc;
        }
    }
}

// ---------------- parallel radix-select: histogram pass ----------------
__global__ void k_hist(const float* __restrict__ scores, const unsigned* __restrict__ selp,
                       unsigned* __restrict__ ghist, int pass) {
    __shared__ unsigned h[256];
    int b = blockIdx.y;
    h[threadIdx.x] = 0u;
    __syncthreads();
    unsigned pref = selp[b];
    unsigned mask = (pass == 3) ? 0u : (0xFFFFFFFFu << ((pass + 1) * 8));
    const unsigned* sb = (const unsigned*)(scores + (size_t)b * EE);
    int base = blockIdx.x * 2048;
    for (int i = base + threadIdx.x; i < base + 2048; i += 256) {
        unsigned u = sb[i];
        if ((u & mask) == pref) atomicAdd(&h[(u >> (pass * 8)) & 255], 1u);
    }
    __syncthreads();
    unsigned v = h[threadIdx.x];
    if (v) atomicAdd(&ghist[b * 256 + threadIdx.x], v);
}

// ---------------- parallel radix-select: pick digit, reset hist ----------------
__global__ void k_pick(unsigned* __restrict__ ghist, unsigned* __restrict__ selp,
                       int* __restrict__ selr, float* __restrict__ thr, int pass) {
    __shared__ unsigned sh[256];
    int b = blockIdx.x;
    unsigned* gh = ghist + b * 256;
    sh[threadIdx.x] = gh[threadIdx.x];
    __syncthreads();
    if (threadIdx.x == 0) {
        unsigned r = (unsigned)selr[b], cum = 0;
        for (int x = 0; x < 256; ++x) {
            unsigned c = sh[x];
            if (cum + c > r) {
                selp[b] |= (unsigned)x << (pass * 8);
                selr[b] = (int)(r - cum);
                break;
            }
            cum += c;
        }
        if (pass == 0) thr[b] = __uint_as_float(selp[b]);
    }
    __syncthreads();
    gh[threadIdx.x] = 0u;
}

// ---------------- threshold + per-group repair + scatter ----------------
__global__ void k_scatter(const float* __restrict__ scores, const float* __restrict__ thr,
                          const int* __restrict__ src, const int* __restrict__ tgt,
                          const int* __restrict__ mep, float* __restrict__ out) {
    int gid = blockIdx.x * 256 + threadIdx.x;
    int b = gid >> 16;
    int lane = threadIdx.x & 63;
    int j = lane & 15;
    float s = scores[gid];
    float t = thr[b];
    bool above = (s >= t);
    unsigned long long bal = __ballot(above);
    int sub = lane >> 4;
    unsigned int mask16 = (unsigned int)((bal >> (sub * 16)) & 0xFFFFull);
    int active = __popc(mask16);
    int rank = 0;
#pragma unroll
    for (int j2 = 0; j2 < 16; ++j2) {
        float sv = __shfl(s, (lane & 48) + j2, 64);
        rank += (sv > s || (sv == s && j2 < j)) ? 1 : 0;
    }
    int me = *mep;
    int need = (active < me) ? min(me - active, DEGQ) : 0;
    bool keep = above || (rank < need);
    float wgt = keep ? s : 0.0f;
    out[(size_t)b * NN * NN + (size_t)src[gid] * NN + tgt[gid]] = wgt;
}

extern "C" void kernel_launch(void* const* d_in, const int* in_sizes, int n_in,
                              void* d_out, int out_size, void* d_ws, size_t ws_size,
                              hipStream_t stream) {
    const float* nf  = (const float*)d_in[0];
    const int*   src = (const int*)d_in[1];
    const int*   tgt = (const int*)d_in[2];
    const float* Wa1 = (const float*)d_in[3];
    const float* ba1 = (const float*)d_in[4];
    const float* Wa2 = (const float*)d_in[5];
    const float* ba2 = (const float*)d_in[6];
    const float* W1  = (const float*)d_in[7];
    const float* b1  = (const float*)d_in[8];
    const float* g1  = (const float*)d_in[9];
    const float* be1 = (const float*)d_in[10];
    const float* m1  = (const float*)d_in[11];
    const float* v1  = (const float*)d_in[12];
    const float* W2  = (const float*)d_in[13];
    const float* b2  = (const float*)d_in[14];
    const float* g2  = (const float*)d_in[15];
    const float* be2 = (const float*)d_in[16];
    const float* m2  = (const float*)d_in[17];
    const float* v2  = (const float*)d_in[18];
    const float* W3  = (const float*)d_in[19];
    const float* b3  = (const float*)d_in[20];
    const int*   mep = (const int*)d_in[21];

    float* ws = (float*)d_ws;
    float*    xn     = ws + WS_XN;
    float*    uvpq   = ws + WS_UVPQ;
    float*    scores = ws + WS_SCORES;
    float*    thrb   = ws + WS_THR;
    unsigned* selp   = (unsigned*)(ws + WS_SELP);
    int*      selr   = (int*)(ws + WS_SELR);
    unsigned* ghist  = (unsigned*)(ws + WS_GHIST);
    float*    bn     = ws + WS_BN;
    float*    wt     = ws + WS_WT;
    float*    out    = (float*)d_out;

    hipMemsetAsync(d_out, 0, (size_t)out_size * sizeof(float), stream);
    k_prep<<<1, 256, 0, stream>>>(g1, be1, m1, v1, g2, be2, m2, v2, bn, ghist, selp, selr);
    k_wt<<<320, 256, 0, stream>>>(Wa2, W1, W2, wt);
    k_norm<<<(BB * NN) / 4, 256, 0, stream>>>(nf, xn);
    k_uvpq<<<dim3((BB * NN) / 32, 6), 256, 0, stream>>>(xn, Wa1, W1, uvpq);
    k_edge<<<dim3(EE / 64, BB), 512, 0, stream>>>(xn, uvpq, wt, ba1, ba2, b1,
                                                  b2, W3, b3, src, tgt, bn, scores);
    for (int pass = 3; pass >= 0; --pass) {
        k_hist<<<dim3(32, BB), 256, 0, stream>>>(scores, selp, ghist, pass);
        k_pick<<<BB, 256, 0, stream>>>(ghist, selp, selr, thrb, pass);
    }
    k_scatter<<<(BB * EE) / 256, 256, 0, stream>>>(scores, thrb, src, tgt, mep, out);
}

// Round 8
// 842.717 us; speedup vs baseline: 1.1639x; 1.1639x over previous
//
#include <hip/hip_runtime.h>
#include <math.h>

#define BB 4
#define NN 4096
#define DEGQ 16
#define DDIM 128
#define EDIM 256
#define EE (NN*DEGQ)   // 65536
#define STR 68         // LDS row stride in floats (16B-aligned, padded)
#define STR4 17        // STR/4

// ws layout (in floats)
#define WS_XN     0
#define WS_UVPQ   (WS_XN + BB*NN*DDIM)            // per-node u,v,p,q: [B*N][768]
#define WS_SCORES (WS_UVPQ + (size_t)BB*NN*768)
#define WS_THR    (WS_SCORES + (size_t)BB*EE)     // 8 floats
#define WS_SELP   (WS_THR + 8)                    // 4 u32
#define WS_SELR   (WS_SELP + 4)                   // 4 i32
#define WS_GHIST  (WS_SELR + 4)                   // 1024 u32
#define WS_BN     (WS_GHIST + 1024)               // 768 floats

// ---------------- normalize: one wave per node row ----------------
__global__ void k_norm(const float* __restrict__ nf, float* __restrict__ xn) {
    int wave = (blockIdx.x * blockDim.x + threadIdx.x) >> 6;
    int lane = threadIdx.x & 63;
    if (wave >= BB * NN) return;
    const float* row = nf + (size_t)wave * DDIM;
    float2 v = *(const float2*)(row + 2 * lane);
    float ss = v.x * v.x + v.y * v.y;
#pragma unroll
    for (int d = 32; d; d >>= 1) ss += __shfl_xor(ss, d, 64);
    float n = fmaxf(sqrtf(ss), 1e-12f);
    float inv = 1.0f / n;
    float2 o; o.x = v.x * inv; o.y = v.y * inv;
    *(float2*)(xn + (size_t)wave * DDIM + 2 * lane) = o;
}

// ---------------- BN constants + select-state init ----------------
__global__ void k_prep(const float* g1, const float* be1, const float* m1, const float* v1,
                       const float* g2, const float* be2, const float* m2, const float* v2,
                       float* bn, unsigned* ghist, unsigned* selp, int* selr) {
    int c = threadIdx.x;
    ghist[c] = 0u; ghist[256 + c] = 0u; ghist[512 + c] = 0u; ghist[768 + c] = 0u;
    if (c < 4) { selp[c] = 0u; selr[c] = EE / 2 - 1; }
    if (c < 256) {
        float s = g1[c] / sqrtf(v1[c] + 1e-5f);
        bn[c] = s; bn[256 + c] = be1[c] - m1[c] * s;
    }
    if (c < 128) {
        float s = g2[c] / sqrtf(v2[c] + 1e-5f);
        bn[512 + c] = s; bn[640 + c] = be2[c] - m2[c] * s;
    }
}

// ---------------- per-node u,v,p,q = xn @ {Wa1_top, Wa1_bot, W1a, W1b} ----------------
__global__ void k_uvpq(const float* __restrict__ xn, const float* __restrict__ Wa1,
                       const float* __restrict__ W1, float* __restrict__ uvpq) {
    int chunk = blockIdx.y;
    const float* wbase; int wstride; int ocol;
    switch (chunk) {
        case 0: wbase = Wa1;                 wstride = 128; ocol = 0;   break;
        case 1: wbase = Wa1 + 128 * 128;     wstride = 128; ocol = 128; break;
        case 2: wbase = W1;                  wstride = 256; ocol = 256; break;
        case 3: wbase = W1 + 128;            wstride = 256; ocol = 384; break;
        case 4: wbase = W1 + 128 * 256;      wstride = 256; ocol = 512; break;
        default: wbase = W1 + 128 * 256 + 128; wstride = 256; ocol = 640; break;
    }
    int wv = threadIdx.x >> 6, lane = threadIdx.x & 63;
    int nodebase = blockIdx.x * 32 + wv * 8;
    const float* xrow[8];
#pragma unroll
    for (int j = 0; j < 8; ++j) xrow[j] = xn + (size_t)(nodebase + j) * DDIM;
    float acc0[8] = {}, acc1[8] = {};
#pragma unroll 4
    for (int k = 0; k < 128; ++k) {
        float w0 = wbase[k * wstride + lane];
        float w1 = wbase[k * wstride + 64 + lane];
#pragma unroll
        for (int j = 0; j < 8; ++j) {
            float a = xrow[j][k];
            acc0[j] = fmaf(a, w0, acc0[j]);
            acc1[j] = fmaf(a, w1, acc1[j]);
        }
    }
#pragma unroll
    for (int j = 0; j < 8; ++j) {
        float* orow = uvpq + (size_t)(nodebase + j) * 768 + ocol;
        orow[lane] = acc0[j];
        orow[64 + lane] = acc1[j];
    }
}

// ---------------- fused edge pipeline: ZERO-BARRIER wave-private version ----------
// Each wave owns 8 edges end-to-end. LDS layout identical to R2 ([128][STR] h1,
// [128][STR] gT at +128*STR, h2T [256][STR] overlaying both), but every region is
// only touched in the wave's own 8 edge-columns -> no __syncthreads anywhere.
// Intra-wave LDS RAW ordering is enforced by compiler lgkmcnt waits.
__global__ __launch_bounds__(512, 4) void
k_edge(const float* __restrict__ xn, const float* __restrict__ uvpq,
       const float* __restrict__ Wa2, const float* __restrict__ ba1,
       const float* __restrict__ ba2, const float* __restrict__ W1,
       const float* __restrict__ b1, const float* __restrict__ W2,
       const float* __restrict__ b2, const float* __restrict__ W3,
       const float* __restrict__ b3, const int* __restrict__ src,
       const int* __restrict__ tgt, const float* __restrict__ bn,
       float* __restrict__ scores) {
    __shared__ float smem[256 * STR];
    __shared__ int ssrc[64], stgt[64];
    int tid = threadIdx.x;
    int b = blockIdx.y;
    int T0 = blockIdx.x * 64;
    int wv = tid >> 6, lane = tid & 63;
    int ebase = 8 * wv;
    if (lane < 8) {   // wave-private slice of the index arrays
        ssrc[ebase + lane] = src[(size_t)b * EE + T0 + ebase + lane];
        stgt[ebase + lane] = tgt[(size_t)b * EE + T0 + ebase + lane];
    }

    const float* uv = uvpq + (size_t)b * NN * 768;
    const float* xb = xn + (size_t)b * NN * DDIM;
    const float4* A4 = (const float4*)smem;

    // ---- h1 stage: per-wave, 8 edges, coalesced row reads
    {
        float ba1a = ba1[lane], ba1b = ba1[64 + lane];
#pragma unroll
        for (int j = 0; j < 8; ++j) {
            int e = ebase + j;
            const float* ur = uv + (size_t)ssrc[e] * 768;
            const float* vr = uv + (size_t)stgt[e] * 768 + 128;
            smem[lane * STR + e] = fmaxf(ur[lane] + vr[lane] + ba1a, 0.0f);
            smem[(64 + lane) * STR + e] = fmaxf(ur[64 + lane] + vr[64 + lane] + ba1b, 0.0f);
        }
    }

    // ---- GEMV1: a = h1 @ Wa2 (+ba2), softmax over 128, gT[c][e] = |sf-tf|[c]*att[c]
    {
        float acc0[8] = {}, acc1[8] = {};
        const float* wa = Wa2 + lane;
#pragma unroll 4
        for (int k = 0; k < 128; ++k) {
            float w0 = wa[k * 128];
            float w1 = wa[k * 128 + 64];
            float4 hA = A4[k * STR4 + 2 * wv];
            float4 hB = A4[k * STR4 + 2 * wv + 1];
            acc0[0] = fmaf(hA.x, w0, acc0[0]); acc1[0] = fmaf(hA.x, w1, acc1[0]);
            acc0[1] = fmaf(hA.y, w0, acc0[1]); acc1[1] = fmaf(hA.y, w1, acc1[1]);
            acc0[2] = fmaf(hA.z, w0, acc0[2]); acc1[2] = fmaf(hA.z, w1, acc1[2]);
            acc0[3] = fmaf(hA.w, w0, acc0[3]); acc1[3] = fmaf(hA.w, w1, acc1[3]);
            acc0[4] = fmaf(hB.x, w0, acc0[4]); acc1[4] = fmaf(hB.x, w1, acc1[4]);
            acc0[5] = fmaf(hB.y, w0, acc0[5]); acc1[5] = fmaf(hB.y, w1, acc1[5]);
            acc0[6] = fmaf(hB.z, w0, acc0[6]); acc1[6] = fmaf(hB.z, w1, acc1[6]);
            acc0[7] = fmaf(hB.w, w0, acc0[7]); acc1[7] = fmaf(hB.w, w1, acc1[7]);
        }
        float bb0 = ba2[lane], bb1 = ba2[64 + lane];
#pragma unroll
        for (int j = 0; j < 8; ++j) {
            float a0 = acc0[j] + bb0, a1 = acc1[j] + bb1;
            float m = fmaxf(a0, a1);
#pragma unroll
            for (int d = 32; d; d >>= 1) m = fmaxf(m, __shfl_xor(m, d, 64));
            float p0 = expf(a0 - m), p1 = expf(a1 - m);
            float s = p0 + p1;
#pragma unroll
            for (int d = 32; d; d >>= 1) s += __shfl_xor(s, d, 64);
            float inv = 1.0f / s;
            int e = ebase + j;
            const float* xs = xb + (size_t)ssrc[e] * DDIM;
            const float* xt = xb + (size_t)stgt[e] * DDIM;
            float d0 = fabsf(xs[lane] - xt[lane]);
            float d1 = fabsf(xs[64 + lane] - xt[64 + lane]);
            smem[128 * STR + lane * STR + e] = d0 * p0 * inv;
            smem[128 * STR + (64 + lane) * STR + e] = d1 * p1 * inv;
        }
    }

    // ---- GEMV2: c = g @ W1c ; y = c + p_s + q_t + b1 ; h2 = relu(BN1)
    float acc2[8][4] = {};
    {
        const float* wc = W1 + 256 * 256 + lane;
#pragma unroll 2
        for (int k = 0; k < 128; ++k) {
            float w0 = wc[k * 256];
            float w1 = wc[k * 256 + 64];
            float w2 = wc[k * 256 + 128];
            float w3 = wc[k * 256 + 192];
            float4 gA = A4[128 * STR4 + k * STR4 + 2 * wv];
            float4 gB = A4[128 * STR4 + k * STR4 + 2 * wv + 1];
            acc2[0][0] = fmaf(gA.x, w0, acc2[0][0]); acc2[0][1] = fmaf(gA.x, w1, acc2[0][1]);
            acc2[0][2] = fmaf(gA.x, w2, acc2[0][2]); acc2[0][3] = fmaf(gA.x, w3, acc2[0][3]);
            acc2[1][0] = fmaf(gA.y, w0, acc2[1][0]); acc2[1][1] = fmaf(gA.y, w1, acc2[1][1]);
            acc2[1][2] = fmaf(gA.y, w2, acc2[1][2]); acc2[1][3] = fmaf(gA.y, w3, acc2[1][3]);
            acc2[2][0] = fmaf(gA.z, w0, acc2[2][0]); acc2[2][1] = fmaf(gA.z, w1, acc2[2][1]);
            acc2[2][2] = fmaf(gA.z, w2, acc2[2][2]); acc2[2][3] = fmaf(gA.z, w3, acc2[2][3]);
            acc2[3][0] = fmaf(gA.w, w0, acc2[3][0]); acc2[3][1] = fmaf(gA.w, w1, acc2[3][1]);
            acc2[3][2] = fmaf(gA.w, w2, acc2[3][2]); acc2[3][3] = fmaf(gA.w, w3, acc2[3][3]);
            acc2[4][0] = fmaf(gB.x, w0, acc2[4][0]); acc2[4][1] = fmaf(gB.x, w1, acc2[4][1]);
            acc2[4][2] = fmaf(gB.x, w2, acc2[4][2]); acc2[4][3] = fmaf(gB.x, w3, acc2[4][3]);
            acc2[5][0] = fmaf(gB.y, w0, acc2[5][0]); acc2[5][1] = fmaf(gB.y, w1, acc2[5][1]);
            acc2[5][2] = fmaf(gB.y, w2, acc2[5][2]); acc2[5][3] = fmaf(gB.y, w3, acc2[5][3]);
            acc2[6][0] = fmaf(gB.z, w0, acc2[6][0]); acc2[6][1] = fmaf(gB.z, w1, acc2[6][1]);
            acc2[6][2] = fmaf(gB.z, w2, acc2[6][2]); acc2[6][3] = fmaf(gB.z, w3, acc2[6][3]);
            acc2[7][0] = fmaf(gB.w, w0, acc2[7][0]); acc2[7][1] = fmaf(gB.w, w1, acc2[7][1]);
            acc2[7][2] = fmaf(gB.w, w2, acc2[7][2]); acc2[7][3] = fmaf(gB.w, w3, acc2[7][3]);
        }
    }
    {
        float s1v[4], t1v[4], b1v[4];
#pragma unroll
        for (int i = 0; i < 4; ++i) {
            int c = lane + 64 * i;
            s1v[i] = bn[c]; t1v[i] = bn[256 + c]; b1v[i] = b1[c];
        }
        // h2T write overlays h1 rows (dead) and this wave's own gT columns
        // (fully consumed by this wave's GEMV2 k-loop above) -> no barrier.
#pragma unroll
        for (int j = 0; j < 8; ++j) {
            int e = ebase + j;
            const float* pr = uv + (size_t)ssrc[e] * 768 + 256;
            const float* qr = uv + (size_t)stgt[e] * 768 + 512;
#pragma unroll
            for (int i = 0; i < 4; ++i) {
                int c = lane + 64 * i;
                float y = acc2[j][i] + pr[c] + qr[c] + b1v[i];
                smem[c * STR + e] = fmaxf(fmaf(y, s1v[i], t1v[i]), 0.0f);
            }
        }
    }

    // ---- GEMV3: h3 = relu(BN2(h2 @ W2 + b2)); logit = h3 @ W3 + b3; score = sigmoid
    {
        float acc30[8] = {}, acc31[8] = {};
        const float* w2p = W2 + lane;
#pragma unroll 4
        for (int k = 0; k < 256; ++k) {
            float w0 = w2p[k * 128];
            float w1 = w2p[k * 128 + 64];
            float4 hA = A4[k * STR4 + 2 * wv];
            float4 hB = A4[k * STR4 + 2 * wv + 1];
            acc30[0] = fmaf(hA.x, w0, acc30[0]); acc31[0] = fmaf(hA.x, w1, acc31[0]);
            acc30[1] = fmaf(hA.y, w0, acc30[1]); acc31[1] = fmaf(hA.y, w1, acc31[1]);
            acc30[2] = fmaf(hA.z, w0, acc30[2]); acc31[2] = fmaf(hA.z, w1, acc31[2]);
            acc30[3] = fmaf(hA.w, w0, acc30[3]); acc31[3] = fmaf(hA.w, w1, acc31[3]);
            acc30[4] = fmaf(hB.x, w0, acc30[4]); acc31[4] = fmaf(hB.x, w1, acc31[4]);
            acc30[5] = fmaf(hB.y, w0, acc30[5]); acc31[5] = fmaf(hB.y, w1, acc31[5]);
            acc30[6] = fmaf(hB.z, w0, acc30[6]); acc31[6] = fmaf(hB.z, w1, acc31[6]);
            acc30[7] = fmaf(hB.w, w0, acc30[7]); acc31[7] = fmaf(hB.w, w1, acc31[7]);
        }
        float s2a = bn[512 + lane], t2a = bn[640 + lane];
        float s2b = bn[512 + 64 + lane], t2b = bn[640 + 64 + lane];
        float b2a = b2[lane], b2b = b2[64 + lane];
        float w3a = W3[lane], w3b = W3[64 + lane];
        float b3v = b3[0];
#pragma unroll
        for (int j = 0; j < 8; ++j) {
            float h0 = fmaxf(fmaf(acc30[j] + b2a, s2a, t2a), 0.0f);
            float h1 = fmaxf(fmaf(acc31[j] + b2b, s2b, t2b), 0.0f);
            float lp = h0 * w3a + h1 * w3b;
#pragma unroll
            for (int d = 32; d; d >>= 1) lp += __shfl_xor(lp, d, 64);
            float sc = 1.0f / (1.0f + expf(-(lp + b3v)));
            if (lane == j) scores[(size_t)b * EE + T0 + ebase + j] = sc;
        }
    }
}

// ---------------- parallel radix-select: histogram pass ----------------
__global__ void k_hist(const float* __restrict__ scores, const unsigned* __restrict__ selp,
                       unsigned* __restrict__ ghist, int pass) {
    __shared__ unsigned h[256];
    int b = blockIdx.y;
    h[threadIdx.x] = 0u;
    __syncthreads();
    unsigned pref = selp[b];
    unsigned mask = (pass == 3) ? 0u : (0xFFFFFFFFu << ((pass + 1) * 8));
    const unsigned* sb = (const unsigned*)(scores + (size_t)b * EE);
    int base = blockIdx.x * 2048;
    for (int i = base + threadIdx.x; i < base + 2048; i += 256) {
        unsigned u = sb[i];
        if ((u & mask) == pref) atomicAdd(&h[(u >> (pass * 8)) & 255], 1u);
    }
    __syncthreads();
    unsigned v = h[threadIdx.x];
    if (v) atomicAdd(&ghist[b * 256 + threadIdx.x], v);
}

// ---------------- parallel radix-select: pick digit, reset hist ----------------
__global__ void k_pick(unsigned* __restrict__ ghist, unsigned* __restrict__ selp,
                       int* __restrict__ selr, float* __restrict__ thr, int pass) {
    __shared__ unsigned sh[256];
    int b = blockIdx.x;
    unsigned* gh = ghist + b * 256;
    sh[threadIdx.x] = gh[threadIdx.x];
    __syncthreads();
    if (threadIdx.x == 0) {
        unsigned r = (unsigned)selr[b], cum = 0;
        for (int x = 0; x < 256; ++x) {
            unsigned c = sh[x];
            if (cum + c > r) {
                selp[b] |= (unsigned)x << (pass * 8);
                selr[b] = (int)(r - cum);
                break;
            }
            cum += c;
        }
        if (pass == 0) thr[b] = __uint_as_float(selp[b]);
    }
    __syncthreads();
    gh[threadIdx.x] = 0u;
}

// ---------------- threshold + per-group repair + scatter ----------------
__global__ void k_scatter(const float* __restrict__ scores, const float* __restrict__ thr,
                          const int* __restrict__ src, const int* __restrict__ tgt,
                          const int* __restrict__ mep, float* __restrict__ out) {
    int gid = blockIdx.x * 256 + threadIdx.x;
    int b = gid >> 16;
    int lane = threadIdx.x & 63;
    int j = lane & 15;
    float s = scores[gid];
    float t = thr[b];
    bool above = (s >= t);
    unsigned long long bal = __ballot(above);
    int sub = lane >> 4;
    unsigned int mask16 = (unsigned int)((bal >> (sub * 16)) & 0xFFFFull);
    int active = __popc(mask16);
    int rank = 0;
#pragma unroll
    for (int j2 = 0; j2 < 16; ++j2) {
        float sv = __shfl(s, (lane & 48) + j2, 64);
        rank += (sv > s || (sv == s && j2 < j)) ? 1 : 0;
    }
    int me = *mep;
    int need = (active < me) ? min(me - active, DEGQ) : 0;
    bool keep = above || (rank < need);
    float wgt = keep ? s : 0.0f;
    out[(size_t)b * NN * NN + (size_t)src[gid] * NN + tgt[gid]] = wgt;
}

extern "C" void kernel_launch(void* const* d_in, const int* in_sizes, int n_in,
                              void* d_out, int out_size, void* d_ws, size_t ws_size,
                              hipStream_t stream) {
    const float* nf  = (const float*)d_in[0];
    const int*   src = (const int*)d_in[1];
    const int*   tgt = (const int*)d_in[2];
    const float* Wa1 = (const float*)d_in[3];
    const float* ba1 = (const float*)d_in[4];
    const float* Wa2 = (const float*)d_in[5];
    const float* ba2 = (const float*)d_in[6];
    const float* W1  = (const float*)d_in[7];
    const float* b1  = (const float*)d_in[8];
    const float* g1  = (const float*)d_in[9];
    const float* be1 = (const float*)d_in[10];
    const float* m1  = (const float*)d_in[11];
    const float* v1  = (const float*)d_in[12];
    const float* W2  = (const float*)d_in[13];
    const float* b2  = (const float*)d_in[14];
    const float* g2  = (const float*)d_in[15];
    const float* be2 = (const float*)d_in[16];
    const float* m2  = (const float*)d_in[17];
    const float* v2  = (const float*)d_in[18];
    const float* W3  = (const float*)d_in[19];
    const float* b3  = (const float*)d_in[20];
    const int*   mep = (const int*)d_in[21];

    float* ws = (float*)d_ws;
    float*    xn     = ws + WS_XN;
    float*    uvpq   = ws + WS_UVPQ;
    float*    scores = ws + WS_SCORES;
    float*    thrb   = ws + WS_THR;
    unsigned* selp   = (unsigned*)(ws + WS_SELP);
    int*      selr   = (int*)(ws + WS_SELR);
    unsigned* ghist  = (unsigned*)(ws + WS_GHIST);
    float*    bn     = ws + WS_BN;
    float*    out    = (float*)d_out;

    hipMemsetAsync(d_out, 0, (size_t)out_size * sizeof(float), stream);
    k_prep<<<1, 256, 0, stream>>>(g1, be1, m1, v1, g2, be2, m2, v2, bn, ghist, selp, selr);
    k_norm<<<(BB * NN) / 4, 256, 0, stream>>>(nf, xn);
    k_uvpq<<<dim3((BB * NN) / 32, 6), 256, 0, stream>>>(xn, Wa1, W1, uvpq);
    k_edge<<<dim3(EE / 64, BB), 512, 0, stream>>>(xn, uvpq, Wa2, ba1, ba2, W1, b1,
                                                  W2, b2, W3, b3, src, tgt, bn, scores);
    for (int pass = 3; pass >= 0; --pass) {
        k_hist<<<dim3(32, BB), 256, 0, stream>>>(scores, selp, ghist, pass);
        k_pick<<<BB, 256, 0, stream>>>(ghist, selp, selr, thrb, pass);
    }
    k_scatter<<<(BB * EE) / 256, 256, 0, stream>>>(scores, thrb, src, tgt, mep, out);
}